// Round 1
// baseline (14335.857 us; speedup 1.0000x reference)
//
#include <hip/hip_runtime.h>
#include <hip/hip_bf16.h>

// Problem constants (from reference): S, B, E, H, V, O = 1024, 256, 128, 256, 32000, 2
#define S_LEN 1024
#define BATCH 256
#define EDIM  128
#define HDIM  256
#define G4H   1024   // 4*H
#define ODIM  2

typedef unsigned int  uint32;

__device__ __forceinline__ float bf_lo(uint32 w) { return __uint_as_float(w << 16); }
__device__ __forceinline__ float bf_hi(uint32 w) { return __uint_as_float(w & 0xffff0000u); }
__device__ __forceinline__ float sigf(float x)   { return 1.0f / (1.0f + __expf(-x)); }
// tanh via exp; saturates correctly for large |x| (exp->inf => 1, exp->0 => -1)
__device__ __forceinline__ float tanhfast(float x) { return 1.0f - 2.0f / (__expf(2.0f * x) + 1.0f); }

__device__ __forceinline__ unsigned short f2bf(float f) {
  uint32 u = __float_as_uint(f);
  return (unsigned short)((u + 0x7fffu + ((u >> 16) & 1u)) >> 16);  // round-to-nearest-even
}

// ws layout:
//   WihP : ushort[EDIM/2][G4H][2]  -> packed pairs along k; uint32 view: [k2][row]
//   WhhP : ushort[HDIM/2][G4H][2]
//   biasc: float[G4H]  = b_ih + b_hh
#define N_WIH (G4H * EDIM)   // 131072
#define N_WHH (G4H * HDIM)   // 262144

__global__ void prep_kernel(const float* __restrict__ w_ih, const float* __restrict__ w_hh,
                            const float* __restrict__ b_ih, const float* __restrict__ b_hh,
                            unsigned short* __restrict__ WihP, unsigned short* __restrict__ WhhP,
                            float* __restrict__ biasc) {
  int id = blockIdx.x * blockDim.x + threadIdx.x;
  if (id < N_WIH) {
    // w_ih is [G4H][EDIM] row-major; id = row*128 + k
    int row = id >> 7, k = id & 127;
    WihP[(k >> 1) * (G4H * 2) + row * 2 + (k & 1)] = f2bf(w_ih[id]);
  } else if (id < N_WIH + N_WHH) {
    int j = id - N_WIH;
    int row = j >> 8, k = j & 255;
    WhhP[(k >> 1) * (G4H * 2) + row * 2 + (k & 1)] = f2bf(w_hh[j]);
  } else if (id < N_WIH + N_WHH + G4H) {
    int i = id - N_WIH - N_WHH;
    biasc[i] = b_ih[i] + b_hh[i];
  }
}

// One block per 2 batch elements; thread tid owns hidden index tid for both.
// Gate rows: i=tid, f=256+tid, g=512+tid, o=768+tid (pytorch i,f,g,o order).
__global__ __launch_bounds__(256) void lstm_kernel(
    const int* __restrict__ inp, const int* __restrict__ lengths,
    const float* __restrict__ h0, const float* __restrict__ c0,
    const float* __restrict__ emb,
    const uint32* __restrict__ wih, const uint32* __restrict__ whh,
    const float* __restrict__ biasc,
    float* __restrict__ outh, float* __restrict__ outc) {
  __shared__ float h_lds[2][HDIM];
  __shared__ float x_lds[2][EDIM];
  const int tid = threadIdx.x;
  const int b0  = blockIdx.x * 2;

  float cc0 = c0[b0 * HDIM + tid];
  float cc1 = c0[(b0 + 1) * HDIM + tid];
  h_lds[0][tid] = h0[b0 * HDIM + tid];
  h_lds[1][tid] = h0[(b0 + 1) * HDIM + tid];

  const float bI = biasc[tid];
  const float bF = biasc[HDIM + tid];
  const float bG = biasc[2 * HDIM + tid];
  const float bO = biasc[3 * HDIM + tid];

  const int len0 = lengths[b0] - 1;
  const int len1 = lengths[b0 + 1] - 1;

  const int xj = tid >> 7, xk = tid & 127;  // x staging: 2 rows x 128 cols
  __syncthreads();

  for (int s = 0; s < S_LEN; ++s) {
    // stage x_t for both batch elements (coalesced 512B per row)
    int tok = inp[s * BATCH + b0 + xj];
    x_lds[xj][xk] = emb[tok * EDIM + xk];
    __syncthreads();  // x ready; h_lds from previous step ready

    float aI0 = bI, aF0 = bF, aG0 = bG, aO0 = bO;
    float aI1 = bI, aF1 = bF, aG1 = bG, aO1 = bO;

    const float2* x0p = (const float2*)x_lds[0];
    const float2* x1p = (const float2*)x_lds[1];
#pragma unroll 4
    for (int k2 = 0; k2 < EDIM / 2; ++k2) {
      const uint32* p = wih + k2 * G4H + tid;
      uint32 wI = p[0];
      uint32 wF = p[HDIM];
      uint32 wG = p[2 * HDIM];
      uint32 wO = p[3 * HDIM];
      float2 xv0 = x0p[k2];
      float2 xv1 = x1p[k2];
      aI0 = fmaf(bf_lo(wI), xv0.x, aI0); aI0 = fmaf(bf_hi(wI), xv0.y, aI0);
      aF0 = fmaf(bf_lo(wF), xv0.x, aF0); aF0 = fmaf(bf_hi(wF), xv0.y, aF0);
      aG0 = fmaf(bf_lo(wG), xv0.x, aG0); aG0 = fmaf(bf_hi(wG), xv0.y, aG0);
      aO0 = fmaf(bf_lo(wO), xv0.x, aO0); aO0 = fmaf(bf_hi(wO), xv0.y, aO0);
      aI1 = fmaf(bf_lo(wI), xv1.x, aI1); aI1 = fmaf(bf_hi(wI), xv1.y, aI1);
      aF1 = fmaf(bf_lo(wF), xv1.x, aF1); aF1 = fmaf(bf_hi(wF), xv1.y, aF1);
      aG1 = fmaf(bf_lo(wG), xv1.x, aG1); aG1 = fmaf(bf_hi(wG), xv1.y, aG1);
      aO1 = fmaf(bf_lo(wO), xv1.x, aO1); aO1 = fmaf(bf_hi(wO), xv1.y, aO1);
    }

    const float2* h0p = (const float2*)h_lds[0];
    const float2* h1p = (const float2*)h_lds[1];
#pragma unroll 4
    for (int k2 = 0; k2 < HDIM / 2; ++k2) {
      const uint32* p = whh + k2 * G4H + tid;
      uint32 wI = p[0];
      uint32 wF = p[HDIM];
      uint32 wG = p[2 * HDIM];
      uint32 wO = p[3 * HDIM];
      float2 hv0 = h0p[k2];
      float2 hv1 = h1p[k2];
      aI0 = fmaf(bf_lo(wI), hv0.x, aI0); aI0 = fmaf(bf_hi(wI), hv0.y, aI0);
      aF0 = fmaf(bf_lo(wF), hv0.x, aF0); aF0 = fmaf(bf_hi(wF), hv0.y, aF0);
      aG0 = fmaf(bf_lo(wG), hv0.x, aG0); aG0 = fmaf(bf_hi(wG), hv0.y, aG0);
      aO0 = fmaf(bf_lo(wO), hv0.x, aO0); aO0 = fmaf(bf_hi(wO), hv0.y, aO0);
      aI1 = fmaf(bf_lo(wI), hv1.x, aI1); aI1 = fmaf(bf_hi(wI), hv1.y, aI1);
      aF1 = fmaf(bf_lo(wF), hv1.x, aF1); aF1 = fmaf(bf_hi(wF), hv1.y, aF1);
      aG1 = fmaf(bf_lo(wG), hv1.x, aG1); aG1 = fmaf(bf_hi(wG), hv1.y, aG1);
      aO1 = fmaf(bf_lo(wO), hv1.x, aO1); aO1 = fmaf(bf_hi(wO), hv1.y, aO1);
    }

    float i0 = sigf(aI0), f0 = sigf(aF0), g0 = tanhfast(aG0), o0 = sigf(aO0);
    cc0 = f0 * cc0 + i0 * g0;
    float hh0 = o0 * tanhfast(cc0);
    float i1 = sigf(aI1), f1 = sigf(aF1), g1 = tanhfast(aG1), o1 = sigf(aO1);
    cc1 = f1 * cc1 + i1 * g1;
    float hh1 = o1 * tanhfast(cc1);

    __syncthreads();  // all readers of h_lds done before overwrite
    h_lds[0][tid] = hh0;
    h_lds[1][tid] = hh1;

    if (s == len0) { outh[b0 * HDIM + tid] = hh0; outc[b0 * HDIM + tid] = cc0; }
    if (s == len1) { outh[(b0 + 1) * HDIM + tid] = hh1; outc[(b0 + 1) * HDIM + tid] = cc1; }
  }
}

// decoded[b][o] = sigmoid(dot(last_h[b,:], dec_w[o,:])), O=2. One 64-lane block per b.
__global__ __launch_bounds__(64) void decode_kernel(const float* __restrict__ outh,
                                                    const float* __restrict__ dec_w,
                                                    float* __restrict__ dec) {
  int b = blockIdx.x, l = threadIdx.x;
  float p0 = 0.f, p1 = 0.f;
#pragma unroll
  for (int m = 0; m < HDIM / 64; ++m) {
    float h = outh[b * HDIM + l + 64 * m];
    p0 = fmaf(h, dec_w[l + 64 * m], p0);
    p1 = fmaf(h, dec_w[HDIM + l + 64 * m], p1);
  }
#pragma unroll
  for (int off = 32; off > 0; off >>= 1) {
    p0 += __shfl_down(p0, off);
    p1 += __shfl_down(p1, off);
  }
  if (l == 0) {
    dec[b * ODIM + 0] = sigf(p0);
    dec[b * ODIM + 1] = sigf(p1);
  }
}

extern "C" void kernel_launch(void* const* d_in, const int* in_sizes, int n_in,
                              void* d_out, int out_size, void* d_ws, size_t ws_size,
                              hipStream_t stream) {
  const int*   inp     = (const int*)d_in[0];
  const int*   lengths = (const int*)d_in[1];
  const float* h0      = (const float*)d_in[2];
  const float* c0      = (const float*)d_in[3];
  const float* emb     = (const float*)d_in[4];
  const float* w_ih    = (const float*)d_in[5];
  const float* w_hh    = (const float*)d_in[6];
  const float* b_ih    = (const float*)d_in[7];
  const float* b_hh    = (const float*)d_in[8];
  const float* dec_w   = (const float*)d_in[9];

  unsigned short* WihP = (unsigned short*)d_ws;
  unsigned short* WhhP = WihP + N_WIH;
  float* biasc = (float*)(WhhP + N_WHH);

  float* dec  = (float*)d_out;                 // [B, 2]
  float* outh = dec + BATCH * ODIM;            // [1, B, H]
  float* outc = outh + BATCH * HDIM;           // [1, B, H]

  int total = N_WIH + N_WHH + G4H;
  prep_kernel<<<(total + 255) / 256, 256, 0, stream>>>(w_ih, w_hh, b_ih, b_hh, WihP, WhhP, biasc);
  lstm_kernel<<<BATCH / 2, 256, 0, stream>>>(inp, lengths, h0, c0, emb,
                                             (const uint32*)WihP, (const uint32*)WhhP, biasc,
                                             outh, outc);
  decode_kernel<<<BATCH, 64, 0, stream>>>(outh, dec_w, dec);
}